// Round 9
// baseline (10754.996 us; speedup 1.0000x reference)
//
#include <hip/hip_runtime.h>
#include <math.h>

#define B_  64
#define T_  1024
#define I_  512
#define O_  512
#define NZ  2048      // 4*O
#define KW  1024      // W row stride (I+O)
#define EPS 1e-5f

#define SREC 32       // recurrent grid: 32 blocks, each owns 16 o-values
#define OSL  16

typedef short bf8_t  __attribute__((ext_vector_type(8)));
typedef float f32x4  __attribute__((ext_vector_type(4)));
typedef unsigned uint4v __attribute__((ext_vector_type(4)));

__device__ __forceinline__ unsigned short f2bf(float f) {
  union { float f; unsigned u; } v; v.f = f;
  unsigned r = v.u + 0x7FFFu + ((v.u >> 16) & 1u);   // RNE
  return (unsigned short)(r >> 16);
}
__device__ __forceinline__ float bf2f(unsigned short b) {
  union { unsigned u; float f; } v; v.u = ((unsigned)b) << 16;
  return v.f;
}

// ---------------------------------------------------------------------------
// K0: zero flag slots, init h (bf16) from init_hx
// ---------------------------------------------------------------------------
__global__ __launch_bounds__(256) void init_all(
    const float* __restrict__ init_hx,
    unsigned short* __restrict__ h, unsigned* __restrict__ sync) {
  int idx = blockIdx.x * 256 + threadIdx.x;
  if (idx < 2048) sync[idx] = 0u;
  if (idx < B_ * O_) h[idx] = f2bf(init_hx[idx & (O_ - 1)]);
}

// ---------------------------------------------------------------------------
// K0b: one-time Wx (rows 0..2047, k 0..511) f32 -> bf16.
// ---------------------------------------------------------------------------
__global__ __launch_bounds__(256) void wx_bf16(
    const float* __restrict__ W, unsigned short* __restrict__ Wbf) {
  int idx = blockIdx.x * 256 + threadIdx.x;   // one float4 each; 262144 total
  int n  = idx >> 7;
  int k4 = (idx & 127) * 4;
  float4 v = *(const float4*)(W + (size_t)n * KW + k4);
  unsigned short* d = Wbf + (size_t)n * 512 + k4;
  d[0] = f2bf(v.x); d[1] = f2bf(v.y); d[2] = f2bf(v.z); d[3] = f2bf(v.w);
}

// ---------------------------------------------------------------------------
// K1: zx = x @ Wx^T with LDS x-reuse + LDS-staged coalesced C-write (R7).
// ---------------------------------------------------------------------------
__global__ __launch_bounds__(256) void zx_gemm(
    const float* __restrict__ x, const unsigned short* __restrict__ Wbf,
    unsigned short* __restrict__ zx) {
  __shared__ unsigned short xl[64 * 520];
  __shared__ unsigned short cst[64 * 72];

  const int tid  = threadIdx.x;
  const int w    = tid >> 6;
  const int lane = tid & 63;
  const int q    = lane >> 4;
  const int col  = lane & 15;
  const int m0   = blockIdx.x * 64;

  for (int e4 = tid; e4 < 64 * 128; e4 += 256) {
    int r  = e4 >> 7;
    int k4 = (e4 & 127) * 4;
    float4 v = *(const float4*)(x + (size_t)(m0 + r) * I_ + k4);
    unsigned short* d = &xl[r * 520 + k4];
    d[0] = f2bf(v.x); d[1] = f2bf(v.y); d[2] = f2bf(v.z); d[3] = f2bf(v.w);
  }
  __syncthreads();

  const unsigned short* __restrict__ arow = &xl[(16 * w + col) * 520];
  const int crow = tid >> 2;
  const int cc0  = (tid & 3) * 16;

  for (int nblk = 0; nblk < 32; ++nblk) {
    const int n0 = nblk * 64;
    f32x4 acc[4];
    #pragma unroll
    for (int i = 0; i < 4; ++i) acc[i] = (f32x4){0.f, 0.f, 0.f, 0.f};

    #pragma unroll
    for (int ks = 0; ks < 16; ++ks) {
      const int k0 = ks * 32 + q * 8;
      bf8_t af = *(const bf8_t*)(arow + k0);
      #pragma unroll
      for (int nt = 0; nt < 4; ++nt) {
        bf8_t bfr = *(const bf8_t*)(Wbf + (size_t)(n0 + nt * 16 + col) * 512 + k0);
        acc[nt] = __builtin_amdgcn_mfma_f32_16x16x32_bf16(af, bfr, acc[nt], 0, 0, 0);
      }
    }
    __syncthreads();
    #pragma unroll
    for (int nt = 0; nt < 4; ++nt)
      #pragma unroll
      for (int r = 0; r < 4; ++r)
        cst[(16 * w + 4 * q + r) * 72 + nt * 16 + col] = f2bf(acc[nt][r]);
    __syncthreads();
    {
      const uint4v* srcp = (const uint4v*)&cst[crow * 72 + cc0];
      uint4v v0 = srcp[0], v1 = srcp[1];
      uint4v* dst = (uint4v*)&zx[(size_t)(m0 + crow) * NZ + n0 + cc0];
      dst[0] = v0; dst[1] = v1;
    }
  }
}

// ---------------------------------------------------------------------------
// K2: recurrent loop — R7's validated protocol, with Wh in REGISTERS.
// R9 change: the Wh LDS tile (stride-520 rows -> 8-way ds_read_b128 bank
// conflicts, SQ_LDS_BANK_CONFLICT=3.36e7 ~= 1025 cyc/block-step, ~1.3us/step
// serialized on the LDS pipe) is replaced by 64 bf8_t fragments in VGPRs
// (256 VGPR; __launch_bounds__(256,1) -> 512-VGPR budget; occupancy already
// 1 wave/SIMD so no loss). All staging/gather via plain HIP loads — no
// inline-asm memory ops anywhere (R4-6 lesson). Sync = R3/R7 flag protocol
// verbatim (sc1 agent-scope, monotonic flags, 32-line gather poll,
// __syncthreads vmcnt-drain release).
// ---------------------------------------------------------------------------
__global__ __launch_bounds__(256, 1) void lstm_rec(
    const float* __restrict__ W, const float* __restrict__ gamma,
    const float* __restrict__ beta, const float* __restrict__ init_cx,
    const unsigned short* __restrict__ zx, unsigned short* __restrict__ h,
    unsigned long long* __restrict__ part8, float* __restrict__ out,
    unsigned* __restrict__ flags) {

  const int tid  = threadIdx.x;
  const int w    = tid >> 6;
  const int lane = tid & 63;
  const int q    = lane >> 4;
  const int col  = lane & 15;
  const int s    = blockIdx.x;
  const int o    = s * OSL + col;

  // ---- Wh fragments -> registers (64 x bf8_t = 256 VGPR), one-time.
  // Fragment (ks,g): B-operand rows n' = col of W[512g + 16s + col][I_+ks*32+q*8..+8)
  bf8_t wh[64];
  #pragma unroll
  for (int ks = 0; ks < 16; ++ks)
    #pragma unroll
    for (int g = 0; g < 4; ++g) {
      const float* wr = W + (size_t)(512 * g + OSL * s + col) * KW + I_ + ks * 32 + q * 8;
      float4 b0 = *(const float4*)(wr);
      float4 b1 = *(const float4*)(wr + 4);
      bf8_t tf;
      tf[0] = (short)f2bf(b0.x); tf[1] = (short)f2bf(b0.y);
      tf[2] = (short)f2bf(b0.z); tf[3] = (short)f2bf(b0.w);
      tf[4] = (short)f2bf(b1.x); tf[5] = (short)f2bf(b1.y);
      tf[6] = (short)f2bf(b1.z); tf[7] = (short)f2bf(b1.w);
      wh[ks * 4 + g] = tf;
    }

  float gma[4], bta[4], c_reg[4];
  #pragma unroll
  for (int g = 0; g < 4; ++g) { gma[g] = gamma[g * O_ + o]; bta[g] = beta[g * O_ + o]; }
  { float c0 = init_cx[o];
    #pragma unroll
    for (int r = 0; r < 4; ++r) c_reg[r] = c0; }

  // ---- prologue: prefetch zx for t=0
  unsigned short zxl[16];
  #pragma unroll
  for (int g = 0; g < 4; ++g)
    #pragma unroll
    for (int r = 0; r < 4; ++r) {
      int b = 16 * w + 4 * q + r;
      zxl[g * 4 + r] = zx[((size_t)b * T_ + 0) * NZ + g * O_ + OSL * s + col];
    }

  __syncthreads();

  for (int t = 0; t < T_; ++t) {
    // ---- gather full h fragment set (sc1 read-through; fresh after bar2)
    unsigned long long araw[32];
    const unsigned short* hrow = h + (16 * w + col) * O_;
    #pragma unroll
    for (int ks = 0; ks < 16; ++ks) {
      const unsigned long long* p =
          (const unsigned long long*)(hrow + ks * 32 + q * 8);
      araw[2 * ks]     = __hip_atomic_load(p,     __ATOMIC_RELAXED, __HIP_MEMORY_SCOPE_AGENT);
      araw[2 * ks + 1] = __hip_atomic_load(p + 1, __ATOMIC_RELAXED, __HIP_MEMORY_SCOPE_AGENT);
    }

    // ---- z-slice = h @ Wh^T  (16x16x32 bf16 MFMA; B-operand from registers)
    f32x4 acc[4];
    #pragma unroll
    for (int g = 0; g < 4; ++g) acc[g] = (f32x4){0.f, 0.f, 0.f, 0.f};

    #pragma unroll
    for (int ks = 0; ks < 16; ++ks) {
      union { unsigned long long u[2]; bf8_t v; } au;
      au.u[0] = araw[2 * ks]; au.u[1] = araw[2 * ks + 1];
      #pragma unroll
      for (int g = 0; g < 4; ++g)
        acc[g] = __builtin_amdgcn_mfma_f32_16x16x32_bf16(au.v, wh[ks * 4 + g], acc[g], 0, 0, 0);
    }

    // ---- z = acc + zx; block-partial LN sums per batch row
    float z[16];
    float s1[4], s2[4];
    #pragma unroll
    for (int r = 0; r < 4; ++r) { s1[r] = 0.f; s2[r] = 0.f; }
    #pragma unroll
    for (int g = 0; g < 4; ++g)
      #pragma unroll
      for (int r = 0; r < 4; ++r) {
        float zv = acc[g][r] + bf2f(zxl[g * 4 + r]);
        z[g * 4 + r] = zv;
        s1[r] += zv;
        s2[r] += zv * zv;
      }
    #pragma unroll
    for (int m = 1; m < 16; m <<= 1) {
      #pragma unroll
      for (int r = 0; r < 4; ++r) {
        s1[r] += __shfl_xor(s1[r], m, 64);
        s2[r] += __shfl_xor(s2[r], m, 64);
      }
    }
    if (col == 0) {
      #pragma unroll
      for (int r = 0; r < 4; ++r) {
        int b = 16 * w + 4 * q + r;
        union { float f[2]; unsigned long long u; } pv;
        pv.f[0] = s1[r]; pv.f[1] = s2[r];
        __hip_atomic_store(&part8[(size_t)s * 64 + b], pv.u,
                           __ATOMIC_RELAXED, __HIP_MEMORY_SCOPE_AGENT);
      }
    }

    // ---- barrier 1: partials ready
    __syncthreads();   // drains vmcnt(0) for all waves -> partials at LLC
    {
      const unsigned tgt = 2u * (unsigned)t + 1u;
      if (tid == 0)
        __hip_atomic_store(&flags[s * 16], tgt,
                           __ATOMIC_RELAXED, __HIP_MEMORY_SCOPE_AGENT);
      const unsigned* fp = &flags[(tid & 31) * 16];
      while (__hip_atomic_load(fp, __ATOMIC_RELAXED, __HIP_MEMORY_SCOPE_AGENT) < tgt) {}
    }

    // ---- distributed LN reduce: lane owns brow = 16w+(lane&15); 8 s-chunks
    float S1 = 0.f, S2 = 0.f;
    {
      const int brow = 16 * w + (lane & 15);
      const int sbase = (lane >> 4) * 8;
      #pragma unroll
      for (int i = 0; i < 8; ++i) {
        union { float f[2]; unsigned long long u; } pv;
        pv.u = __hip_atomic_load(&part8[(size_t)(sbase + i) * 64 + brow],
                                 __ATOMIC_RELAXED, __HIP_MEMORY_SCOPE_AGENT);
        S1 += pv.f[0]; S2 += pv.f[1];
      }
    }
    S1 += __shfl_xor(S1, 16, 64); S2 += __shfl_xor(S2, 16, 64);
    S1 += __shfl_xor(S1, 32, 64); S2 += __shfl_xor(S2, 32, 64);
    float mean_l = S1 * (1.f / NZ);
    float rstd_l = rsqrtf(S2 * (1.f / NZ) - mean_l * mean_l + EPS);

    // ---- gates + state update (mean/rstd pulled from lane 4q+r)
    float hnl[4];
    #pragma unroll
    for (int r = 0; r < 4; ++r) {
      int b = 16 * w + 4 * q + r;
      float mean = __shfl(mean_l, 4 * q + r, 64);
      float rstd = __shfl(rstd_l, 4 * q + r, 64);
      float zn0 = (z[0 * 4 + r] - mean) * rstd * gma[0] + bta[0];
      float zn1 = (z[1 * 4 + r] - mean) * rstd * gma[1] + bta[1];
      float zn2 = (z[2 * 4 + r] - mean) * rstd * gma[2] + bta[2];
      float zn3 = (z[3 * 4 + r] - mean) * rstd * gma[3] + bta[3];
      float fg = 1.f / (1.f + expf(-zn0));
      float ig = 1.f / (1.f + expf(-zn1));
      float og = 1.f / (1.f + expf(-zn2));
      float gg = 0.5f * zn3 * (1.f + erff(zn3 * 0.70710678118654752f));
      float cn = fg * c_reg[r] + ig * gg;
      float hn = og * cn;
      c_reg[r] = cn;
      hnl[r] = hn;
      __hip_atomic_store(&h[b * O_ + o], f2bf(hn),
                         __ATOMIC_RELAXED, __HIP_MEMORY_SCOPE_AGENT);
    }

    // ---- barrier 2: h ready. out stores + zx prefetch live in the shadow.
    if (t + 1 < T_) {
      __syncthreads();   // drains vmcnt(0) -> h stores at LLC
      const unsigned tgt = 2u * (unsigned)t + 2u;
      if (tid == 0)
        __hip_atomic_store(&flags[s * 16], tgt,
                           __ATOMIC_RELAXED, __HIP_MEMORY_SCOPE_AGENT);
      #pragma unroll
      for (int r = 0; r < 4; ++r) {
        int b = 16 * w + 4 * q + r;
        out[((size_t)b * T_ + t) * O_ + o] = hnl[r];
      }
      #pragma unroll
      for (int g = 0; g < 4; ++g)
        #pragma unroll
        for (int r = 0; r < 4; ++r) {
          int b = 16 * w + 4 * q + r;
          zxl[g * 4 + r] =
              zx[((size_t)b * T_ + (t + 1)) * NZ + g * O_ + OSL * s + col];
        }
      const unsigned* fp = &flags[(tid & 31) * 16];
      while (__hip_atomic_load(fp, __ATOMIC_RELAXED, __HIP_MEMORY_SCOPE_AGENT) < tgt) {}
    } else {
      #pragma unroll
      for (int r = 0; r < 4; ++r) {
        int b = 16 * w + 4 * q + r;
        out[((size_t)b * T_ + t) * O_ + o] = hnl[r];
      }
    }
  }
}

// ---------------------------------------------------------------------------
extern "C" void kernel_launch(void* const* d_in, const int* in_sizes, int n_in,
                              void* d_out, int out_size, void* d_ws, size_t ws_size,
                              hipStream_t stream) {
  const float* x       = (const float*)d_in[0];
  const float* W       = (const float*)d_in[1];
  const float* gamma   = (const float*)d_in[2];
  const float* beta    = (const float*)d_in[3];
  const float* init_hx = (const float*)d_in[4];
  const float* init_cx = (const float*)d_in[5];
  float* out = (float*)d_out;
  (void)in_sizes; (void)n_in; (void)out_size; (void)ws_size;

  char* ws = (char*)d_ws;
  unsigned*           flags = (unsigned*)(ws);                        // 8 KB zeroed
  unsigned long long* part8 = (unsigned long long*)(ws + 8192);       // 16 KB
  unsigned short*     h     = (unsigned short*)(ws + 32768);          // 64 KB
  unsigned short*     Wbf   = (unsigned short*)(ws + (1 << 20));      // 2 MB
  unsigned short*     zx    = (unsigned short*)(ws + (4 << 20));      // 256 MB

  init_all<<<128, 256, 0, stream>>>(init_hx, h, flags);
  wx_bf16<<<1024, 256, 0, stream>>>(W, Wbf);
  zx_gemm<<<1024, 256, 0, stream>>>(x, Wbf, zx);
  lstm_rec<<<SREC, 256, 0, stream>>>(W, gamma, beta, init_cx, zx, h, part8, out, flags);
}

// Round 10
// 9375.591 us; speedup vs baseline: 1.1471x; 1.1471x over previous
//
#include <hip/hip_runtime.h>
#include <math.h>

#define B_  64
#define T_  1024
#define I_  512
#define O_  512
#define NZ  2048      // 4*O
#define KW  1024      // W row stride (I+O)
#define EPS 1e-5f

#define SREC 32       // recurrent consumer blocks
#define NPROD 1024    // zx producer blocks (one 64-row tile each)
#define OSL  16
#define BAILOUT (1u << 18)

typedef short bf8_t  __attribute__((ext_vector_type(8)));
typedef float f32x4  __attribute__((ext_vector_type(4)));
typedef unsigned uint4v __attribute__((ext_vector_type(4)));

__device__ __forceinline__ unsigned short f2bf(float f) {
  union { float f; unsigned u; } v; v.f = f;
  unsigned r = v.u + 0x7FFFu + ((v.u >> 16) & 1u);   // RNE
  return (unsigned short)(r >> 16);
}
__device__ __forceinline__ float bf2f(unsigned short b) {
  union { unsigned u; float f; } v; v.u = ((unsigned)b) << 16;
  return v.f;
}

// ---------------------------------------------------------------------------
// K0: zero flags (incl. zx chunk counters), init h (bf16) from init_hx
// ---------------------------------------------------------------------------
__global__ __launch_bounds__(256) void init_all(
    const float* __restrict__ init_hx,
    unsigned short* __restrict__ h, unsigned* __restrict__ sync) {
  int idx = blockIdx.x * 256 + threadIdx.x;
  if (idx < 2048) sync[idx] = 0u;
  if (idx < B_ * O_) h[idx] = f2bf(init_hx[idx & (O_ - 1)]);
}

// ---------------------------------------------------------------------------
// K0b: one-time Wx (rows 0..2047, k 0..511) f32 -> bf16.
// ---------------------------------------------------------------------------
__global__ __launch_bounds__(256) void wx_bf16(
    const float* __restrict__ W, unsigned short* __restrict__ Wbf) {
  int idx = blockIdx.x * 256 + threadIdx.x;   // one float4 each; 262144 total
  int n  = idx >> 7;
  int k4 = (idx & 127) * 4;
  float4 v = *(const float4*)(W + (size_t)n * KW + k4);
  unsigned short* d = Wbf + (size_t)n * 512 + k4;
  d[0] = f2bf(v.x); d[1] = f2bf(v.y); d[2] = f2bf(v.z); d[3] = f2bf(v.w);
}

// ---------------------------------------------------------------------------
// FUSED kernel: 32 consumer blocks (R7-validated lstm_rec, LDS Wh, flag-array
// sc1 barriers) + 1024 producer blocks (R7-validated zx_gemm tile).
//
// R10 change: zx production overlaps the recurrence instead of running
// serially before it (~0.9 ms). Producers are numbered t-chunk-major
// (p = b + 64*tchunk) so chunk 0 completes first. Producer protocol:
//   compute tile -> sc1 stores (plain HIP atomics; compiler-tracked) ->
//   __syncthreads (vmcnt drain, release) -> fetch_add(zxcnt[tchunk]).
// Consumer gate: before prefetching zx for t+1 with (t+1)%64==0 (and at the
// t=0 prologue), poll zxcnt[(t+1)/64] >= 64 (wave-uniform sc1 load, bailout).
// Everything else in the consumer is byte-identical to R7's lstm_rec.
// Deadlock-free: producers never spin; consumers leave 224 CUs free.
// ---------------------------------------------------------------------------
__global__ __launch_bounds__(256) void fused_rec(
    const float* __restrict__ x, const unsigned short* __restrict__ Wbf,
    const float* __restrict__ W, const float* __restrict__ gamma,
    const float* __restrict__ beta, const float* __restrict__ init_cx,
    unsigned short* __restrict__ zx, unsigned short* __restrict__ h,
    unsigned long long* __restrict__ part8, float* __restrict__ out,
    unsigned* __restrict__ flags) {

  // one shared pool: consumer uses 33280 shorts (whlds); producer uses
  // 33280 (xl) + 4608 (cst) = 37888 shorts = 75776 B -> 2 producer blocks/CU
  __shared__ unsigned short smem[37888];

  const int tid  = threadIdx.x;
  const int w    = tid >> 6;
  const int lane = tid & 63;
  const int q    = lane >> 4;
  const int col  = lane & 15;
  unsigned* zxcnt = flags + 1024;   // 16 chunk counters (zeroed by init_all)

  if (blockIdx.x >= SREC) {
    // =============== PRODUCER: one 64-row zx tile =======================
    const int p  = blockIdx.x - SREC;       // 0..1023
    const int b  = p & 63;                  // batch
    const int tc = p >> 6;                  // t-chunk 0..15
    const int m0 = b * T_ + tc * 64;        // first row of tile

    unsigned short* xl  = smem;             // [64][520]
    unsigned short* cst = smem + 33280;     // [64][72]

    for (int e4 = tid; e4 < 64 * 128; e4 += 256) {
      int r  = e4 >> 7;
      int k4 = (e4 & 127) * 4;
      float4 v = *(const float4*)(x + (size_t)(m0 + r) * I_ + k4);
      unsigned short* d = &xl[r * 520 + k4];
      d[0] = f2bf(v.x); d[1] = f2bf(v.y); d[2] = f2bf(v.z); d[3] = f2bf(v.w);
    }
    __syncthreads();

    const unsigned short* arow = &xl[(16 * w + col) * 520];
    const int crow = tid >> 2;
    const int cc0  = (tid & 3) * 16;

    for (int nblk = 0; nblk < 32; ++nblk) {
      const int n0 = nblk * 64;
      f32x4 acc[4];
      #pragma unroll
      for (int i = 0; i < 4; ++i) acc[i] = (f32x4){0.f, 0.f, 0.f, 0.f};

      #pragma unroll
      for (int ks = 0; ks < 16; ++ks) {
        const int k0 = ks * 32 + q * 8;
        bf8_t af = *(const bf8_t*)(arow + k0);
        #pragma unroll
        for (int nt = 0; nt < 4; ++nt) {
          bf8_t bfr = *(const bf8_t*)(Wbf + (size_t)(n0 + nt * 16 + col) * 512 + k0);
          acc[nt] = __builtin_amdgcn_mfma_f32_16x16x32_bf16(af, bfr, acc[nt], 0, 0, 0);
        }
      }
      __syncthreads();
      #pragma unroll
      for (int nt = 0; nt < 4; ++nt)
        #pragma unroll
        for (int r = 0; r < 4; ++r)
          cst[(16 * w + 4 * q + r) * 72 + nt * 16 + col] = f2bf(acc[nt][r]);
      __syncthreads();
      {
        union { uint4v v; unsigned long long u[2]; } a0, a1;
        const uint4v* srcp = (const uint4v*)&cst[crow * 72 + cc0];
        a0.v = srcp[0]; a1.v = srcp[1];
        unsigned long long* dst =
            (unsigned long long*)&zx[(size_t)(m0 + crow) * NZ + n0 + cc0];
        __hip_atomic_store(dst + 0, a0.u[0], __ATOMIC_RELAXED, __HIP_MEMORY_SCOPE_AGENT);
        __hip_atomic_store(dst + 1, a0.u[1], __ATOMIC_RELAXED, __HIP_MEMORY_SCOPE_AGENT);
        __hip_atomic_store(dst + 2, a1.u[0], __ATOMIC_RELAXED, __HIP_MEMORY_SCOPE_AGENT);
        __hip_atomic_store(dst + 3, a1.u[1], __ATOMIC_RELAXED, __HIP_MEMORY_SCOPE_AGENT);
      }
    }
    __syncthreads();   // drains vmcnt(0) for all waves -> tile at LLC
    if (tid == 0)
      __hip_atomic_fetch_add(&zxcnt[tc], 1u, __ATOMIC_RELAXED,
                             __HIP_MEMORY_SCOPE_AGENT);
    return;
  }

  // =============== CONSUMER: R7-validated recurrent loop ================
  unsigned short* whlds = smem;   // [64][520]
  const int s = blockIdx.x;
  const int o = s * OSL + col;

  // ---- stage Wh slice -> LDS (once)
  for (int e4 = tid; e4 < 64 * 128; e4 += 256) {
    int r  = e4 >> 7;
    int k4 = (e4 & 127) * 4;
    int g  = r >> 4, np = r & 15;
    const float4 v =
        *(const float4*)(W + (size_t)(512 * g + OSL * s + np) * KW + I_ + k4);
    unsigned short* d = &whlds[r * 520 + k4];
    d[0] = f2bf(v.x); d[1] = f2bf(v.y); d[2] = f2bf(v.z); d[3] = f2bf(v.w);
  }

  float gma[4], bta[4], c_reg[4];
  #pragma unroll
  for (int g = 0; g < 4; ++g) { gma[g] = gamma[g * O_ + o]; bta[g] = beta[g * O_ + o]; }
  { float c0 = init_cx[o];
    #pragma unroll
    for (int r = 0; r < 4; ++r) c_reg[r] = c0; }

  // ---- prologue: wait for zx chunk 0, then prefetch zx for t=0
  {
    unsigned spins = 0;
    while (__hip_atomic_load(&zxcnt[0], __ATOMIC_RELAXED,
                             __HIP_MEMORY_SCOPE_AGENT) < 64u) {
      if (++spins > BAILOUT) break;
    }
  }
  unsigned short zxl[16];
  #pragma unroll
  for (int g = 0; g < 4; ++g)
    #pragma unroll
    for (int r = 0; r < 4; ++r) {
      int b = 16 * w + 4 * q + r;
      zxl[g * 4 + r] = zx[((size_t)b * T_ + 0) * NZ + g * O_ + OSL * s + col];
    }

  __syncthreads();

  for (int t = 0; t < T_; ++t) {
    // ---- gather full h fragment set (sc1 read-through; fresh after bar2)
    unsigned long long araw[32];
    const unsigned short* hrow = h + (16 * w + col) * O_;
    #pragma unroll
    for (int ks = 0; ks < 16; ++ks) {
      const unsigned long long* p =
          (const unsigned long long*)(hrow + ks * 32 + q * 8);
      araw[2 * ks]     = __hip_atomic_load(p,     __ATOMIC_RELAXED, __HIP_MEMORY_SCOPE_AGENT);
      araw[2 * ks + 1] = __hip_atomic_load(p + 1, __ATOMIC_RELAXED, __HIP_MEMORY_SCOPE_AGENT);
    }

    // ---- z-slice = h @ Wh^T  (16x16x32 bf16 MFMA; Wh from LDS)
    f32x4 acc[4];
    #pragma unroll
    for (int g = 0; g < 4; ++g) acc[g] = (f32x4){0.f, 0.f, 0.f, 0.f};

    #pragma unroll
    for (int ks = 0; ks < 16; ++ks) {
      union { unsigned long long u[2]; bf8_t v; } au;
      au.u[0] = araw[2 * ks]; au.u[1] = araw[2 * ks + 1];
      #pragma unroll
      for (int g = 0; g < 4; ++g) {
        bf8_t bfr = *(const bf8_t*)(&whlds[(g * 16 + col) * 520 + ks * 32 + q * 8]);
        acc[g] = __builtin_amdgcn_mfma_f32_16x16x32_bf16(au.v, bfr, acc[g], 0, 0, 0);
      }
    }

    // ---- z = acc + zx; block-partial LN sums per batch row
    float z[16];
    float s1[4], s2[4];
    #pragma unroll
    for (int r = 0; r < 4; ++r) { s1[r] = 0.f; s2[r] = 0.f; }
    #pragma unroll
    for (int g = 0; g < 4; ++g)
      #pragma unroll
      for (int r = 0; r < 4; ++r) {
        float zv = acc[g][r] + bf2f(zxl[g * 4 + r]);
        z[g * 4 + r] = zv;
        s1[r] += zv;
        s2[r] += zv * zv;
      }
    #pragma unroll
    for (int m = 1; m < 16; m <<= 1) {
      #pragma unroll
      for (int r = 0; r < 4; ++r) {
        s1[r] += __shfl_xor(s1[r], m, 64);
        s2[r] += __shfl_xor(s2[r], m, 64);
      }
    }
    if (col == 0) {
      #pragma unroll
      for (int r = 0; r < 4; ++r) {
        int b = 16 * w + 4 * q + r;
        union { float f[2]; unsigned long long u; } pv;
        pv.f[0] = s1[r]; pv.f[1] = s2[r];
        __hip_atomic_store(&part8[(size_t)s * 64 + b], pv.u,
                           __ATOMIC_RELAXED, __HIP_MEMORY_SCOPE_AGENT);
      }
    }

    // ---- barrier 1: partials ready
    __syncthreads();   // drains vmcnt(0) for all waves -> partials at LLC
    {
      const unsigned tgt = 2u * (unsigned)t + 1u;
      if (tid == 0)
        __hip_atomic_store(&flags[s * 16], tgt,
                           __ATOMIC_RELAXED, __HIP_MEMORY_SCOPE_AGENT);
      const unsigned* fp = &flags[(tid & 31) * 16];
      while (__hip_atomic_load(fp, __ATOMIC_RELAXED, __HIP_MEMORY_SCOPE_AGENT) < tgt) {}
    }

    // ---- distributed LN reduce: lane owns brow = 16w+(lane&15); 8 s-chunks
    float S1 = 0.f, S2 = 0.f;
    {
      const int brow = 16 * w + (lane & 15);
      const int sbase = (lane >> 4) * 8;
      #pragma unroll
      for (int i = 0; i < 8; ++i) {
        union { float f[2]; unsigned long long u; } pv;
        pv.u = __hip_atomic_load(&part8[(size_t)(sbase + i) * 64 + brow],
                                 __ATOMIC_RELAXED, __HIP_MEMORY_SCOPE_AGENT);
        S1 += pv.f[0]; S2 += pv.f[1];
      }
    }
    S1 += __shfl_xor(S1, 16, 64); S2 += __shfl_xor(S2, 16, 64);
    S1 += __shfl_xor(S1, 32, 64); S2 += __shfl_xor(S2, 32, 64);
    float mean_l = S1 * (1.f / NZ);
    float rstd_l = rsqrtf(S2 * (1.f / NZ) - mean_l * mean_l + EPS);

    // ---- gates + state update (mean/rstd pulled from lane 4q+r)
    float hnl[4];
    #pragma unroll
    for (int r = 0; r < 4; ++r) {
      int b = 16 * w + 4 * q + r;
      float mean = __shfl(mean_l, 4 * q + r, 64);
      float rstd = __shfl(rstd_l, 4 * q + r, 64);
      float zn0 = (z[0 * 4 + r] - mean) * rstd * gma[0] + bta[0];
      float zn1 = (z[1 * 4 + r] - mean) * rstd * gma[1] + bta[1];
      float zn2 = (z[2 * 4 + r] - mean) * rstd * gma[2] + bta[2];
      float zn3 = (z[3 * 4 + r] - mean) * rstd * gma[3] + bta[3];
      float fg = 1.f / (1.f + expf(-zn0));
      float ig = 1.f / (1.f + expf(-zn1));
      float og = 1.f / (1.f + expf(-zn2));
      float gg = 0.5f * zn3 * (1.f + erff(zn3 * 0.70710678118654752f));
      float cn = fg * c_reg[r] + ig * gg;
      float hn = og * cn;
      c_reg[r] = cn;
      hnl[r] = hn;
      __hip_atomic_store(&h[b * O_ + o], f2bf(hn),
                         __ATOMIC_RELAXED, __HIP_MEMORY_SCOPE_AGENT);
    }

    // ---- barrier 2: h ready. out stores + zx prefetch live in the shadow.
    if (t + 1 < T_) {
      __syncthreads();   // drains vmcnt(0) -> h stores at LLC
      const unsigned tgt = 2u * (unsigned)t + 2u;
      if (tid == 0)
        __hip_atomic_store(&flags[s * 16], tgt,
                           __ATOMIC_RELAXED, __HIP_MEMORY_SCOPE_AGENT);
      #pragma unroll
      for (int r = 0; r < 4; ++r) {
        int b = 16 * w + 4 * q + r;
        out[((size_t)b * T_ + t) * O_ + o] = hnl[r];
      }
      // gate on producer chunk at chunk boundaries, then prefetch zx(t+1)
      if (((t + 1) & 63) == 0) {
        const int tc = (t + 1) >> 6;
        unsigned spins = 0;
        while (__hip_atomic_load(&zxcnt[tc], __ATOMIC_RELAXED,
                                 __HIP_MEMORY_SCOPE_AGENT) < 64u) {
          if (++spins > BAILOUT) break;
        }
      }
      #pragma unroll
      for (int g = 0; g < 4; ++g)
        #pragma unroll
        for (int r = 0; r < 4; ++r) {
          int b = 16 * w + 4 * q + r;
          zxl[g * 4 + r] =
              zx[((size_t)b * T_ + (t + 1)) * NZ + g * O_ + OSL * s + col];
        }
      const unsigned* fp = &flags[(tid & 31) * 16];
      while (__hip_atomic_load(fp, __ATOMIC_RELAXED, __HIP_MEMORY_SCOPE_AGENT) < tgt) {}
    } else {
      #pragma unroll
      for (int r = 0; r < 4; ++r) {
        int b = 16 * w + 4 * q + r;
        out[((size_t)b * T_ + t) * O_ + o] = hnl[r];
      }
    }
  }
}

// ---------------------------------------------------------------------------
extern "C" void kernel_launch(void* const* d_in, const int* in_sizes, int n_in,
                              void* d_out, int out_size, void* d_ws, size_t ws_size,
                              hipStream_t stream) {
  const float* x       = (const float*)d_in[0];
  const float* W       = (const float*)d_in[1];
  const float* gamma   = (const float*)d_in[2];
  const float* beta    = (const float*)d_in[3];
  const float* init_hx = (const float*)d_in[4];
  const float* init_cx = (const float*)d_in[5];
  float* out = (float*)d_out;
  (void)in_sizes; (void)n_in; (void)out_size; (void)ws_size;

  char* ws = (char*)d_ws;
  unsigned*           flags = (unsigned*)(ws);                        // 8 KB zeroed (incl zxcnt @ +4KB)
  unsigned long long* part8 = (unsigned long long*)(ws + 8192);       // 16 KB
  unsigned short*     h     = (unsigned short*)(ws + 32768);          // 64 KB
  unsigned short*     Wbf   = (unsigned short*)(ws + (1 << 20));      // 2 MB
  unsigned short*     zx    = (unsigned short*)(ws + (4 << 20));      // 256 MB

  init_all<<<128, 256, 0, stream>>>(init_hx, h, flags);
  wx_bf16<<<1024, 256, 0, stream>>>(W, Wbf);
  fused_rec<<<SREC + NPROD, 256, 0, stream>>>(x, Wbf, W, gamma, beta, init_cx,
                                              zx, h, part8, out, flags);
}